// Round 11
// baseline (198.692 us; speedup 1.0000x reference)
//
#include <hip/hip_runtime.h>
#include <math.h>

// P=256, T=65536, UNITS=128, WIDTH=1.0
#define Pn 256
#define Tn 65536
#define Un 128
#define NC 512          // scan chunks
#define CHUNK 128       // Tn / NC
#define ST 16           // kC GEMM sub-tile depth (double-buffered)

typedef float f4 __attribute__((ext_vector_type(4)));
typedef float f2 __attribute__((ext_vector_type(2)));

// ---------------------------------------------------------------------------
// Play step: s' = Phi(x - s) + s  ==  min(max(s, x), x+1)   [min LAST].
// Operator (A,B): s -> min(max(s,A),B). Element x -> (x, x+1).
// compose(first=(A1,B1), then=(A2,B2)): A = max(A1,A2); B = min(max(B1,A2),B2).
// ---------------------------------------------------------------------------

// kA: one wave per (p, chunk). Coalesced f2 loads (512B/wave), lane composes
// its 2 ordered elements, then ordered 6-step shfl_down tree (self=first).
// Writes operators row-major AB[p][c] for kB's contiguous per-row read.
__global__ __launch_bounds__(1024) void kA(const float* __restrict__ in,
                                           const float* __restrict__ pw,
                                           f2* __restrict__ AB) {
  const int tid = threadIdx.x;
  const int W = blockIdx.x * 16 + (tid >> 6);  // global wave id, [0, Pn*NC)
  const int l = tid & 63;
  const int c = W & (NC - 1);
  const int p = W >> 9;                        // W / NC
  const float w = pw[p];
  f2 v = *(const f2*)(in + (size_t)p * Tn + (size_t)c * CHUNK + 2 * l);
  const float x0 = v.x * w, x1 = v.y * w;
  float A = fmaxf(x0, x1);
  float B = fminf(fmaxf(x0 + 1.0f, x1), x1 + 1.0f);
#pragma unroll
  for (int off = 1; off < 64; off <<= 1) {
    float A2 = __shfl_down(A, off);   // received = "then" (later elements)
    float B2 = __shfl_down(B, off);
    B = fminf(fmaxf(B, A2), B2);
    A = fmaxf(A, A2);
  }
  if (l == 0) {
    f2 r; r.x = A; r.y = B;
    AB[(size_t)p * NC + c] = r;
  }
}

// kB: per-row parallel (Hillis-Steele) inclusive scan over NC chunk operators.
// 256 blocks (one per row p), NC threads. Non-commutative compose, left=first.
// Thread c writes the INCOMING state of chunk c: sinb[c][p].
__global__ __launch_bounds__(NC) void kB(const f2* __restrict__ AB,
                                         const float* __restrict__ st,
                                         float* __restrict__ sinb) {
  __shared__ float sA[NC], sB[NC];
  const int p = blockIdx.x;
  const int c = threadIdx.x;
  f2 ab = AB[(size_t)p * NC + c];
  sA[c] = ab.x;
  sB[c] = ab.y;
  __syncthreads();
#pragma unroll
  for (int d = 1; d < NC; d <<= 1) {
    float aL = 0.0f, bL = 0.0f;
    const bool has = (c >= d);
    if (has) { aL = sA[c - d]; bL = sB[c - d]; }
    __syncthreads();
    if (has) {
      float aS = sA[c], bS = sB[c];
      sB[c] = fminf(fmaxf(bL, aS), bS);   // compose(left THEN self)
      sA[c] = fmaxf(aL, aS);
    }
    __syncthreads();
  }
  const float s0 = st[p];
  const float sin_c =
      (c == 0) ? s0 : fminf(fmaxf(s0, sA[c - 1]), sB[c - 1]);
  sinb[(size_t)c * Pn + p] = sin_c;
}

// ---------------------------------------------------------------------------
// kC: rescan chunk with correct incoming state + fused f32 GEMM.
// 512 threads (8 waves). Double-buffered LDS (ST=16), async-stage split:
// next-subtile global loads issued BEFORE the GEMM, written after, one
// barrier per subtile. Thread (pg,ug) owns p in {k1*128+pg*4+a},
// u in {k2*64+ug*4+l}: acc[2][4][2][4] = 64 VGPR.  (unchanged from R8/R9)
// ---------------------------------------------------------------------------
template <int CPG, bool ATOMIC>
__global__ __launch_bounds__(512, 4) void kC(const float* __restrict__ in,
                                             const float* __restrict__ pw,
                                             const float* __restrict__ Kg,
                                             const float* __restrict__ sinb,
                                             float* __restrict__ outp) {
  __shared__ float sS[2][ST][Pn];   // 32 KB
  __shared__ float sK[2][ST][Un];   // 16 KB
  const int tid = threadIdx.x;
  const int c0 = blockIdx.x * CPG;

  float w = 0.0f, s = 0.0f;
  const f4* src = nullptr;
  if (tid < Pn) {
    w = pw[tid];
    s = sinb[(size_t)c0 * Pn + tid];
    src = (const f4*)(in + (size_t)tid * Tn + (size_t)c0 * CHUNK);
  }

  const int ug = tid & 15, pg = tid >> 4;
  const int kr = tid >> 5, kcol = tid & 31;   // K-stage: 16 rows x 32 f4
  const f4* Kt = (const f4*)(Kg + (size_t)c0 * CHUNK * Un);

  float acc[2][4][2][4];
#pragma unroll
  for (int k1 = 0; k1 < 2; ++k1)
#pragma unroll
    for (int a = 0; a < 4; ++a)
#pragma unroll
      for (int k2 = 0; k2 < 2; ++k2)
#pragma unroll
        for (int l = 0; l < 4; ++l) acc[k1][a][k2][l] = 0.0f;

  const int nsub = (CHUNK * CPG) / ST;

  // prologue: stage subtile 0 into buffer 0
  {
    f4 kv = Kt[kr * 32 + kcol];
    *(f4*)&sK[0][kr][kcol * 4] = kv;
    if (tid < Pn) {
#pragma unroll
      for (int i4 = 0; i4 < ST / 4; ++i4) {
        f4 v = src[i4];
#pragma unroll
        for (int j = 0; j < 4; ++j) {
          float x = v[j] * w;
          s = fminf(fmaxf(s, x), x + 1.0f);
          sS[0][i4 * 4 + j][tid] = s;
        }
      }
    }
  }
  __syncthreads();

  int b = 0;
  for (int sub = 0; sub < nsub; ++sub) {
    f4 kpre;
    f4 spre0, spre1, spre2, spre3;
    const bool more = (sub + 1 < nsub);
    if (more) {
      kpre = Kt[(sub + 1) * (ST * Un / 4) + kr * 32 + kcol];
      if (tid < Pn) {
        spre0 = src[(sub + 1) * (ST / 4) + 0];
        spre1 = src[(sub + 1) * (ST / 4) + 1];
        spre2 = src[(sub + 1) * (ST / 4) + 2];
        spre3 = src[(sub + 1) * (ST / 4) + 3];
      }
    }

    const float(*cs)[Pn] = sS[b];
    const float(*ck)[Un] = sK[b];
#pragma unroll 4
    for (int i = 0; i < ST; ++i) {
      f4 sv0 = *(const f4*)&cs[i][pg * 4];
      f4 sv1 = *(const f4*)&cs[i][128 + pg * 4];
      f4 kv0 = *(const f4*)&ck[i][ug * 4];
      f4 kv1 = *(const f4*)&ck[i][64 + ug * 4];
#pragma unroll
      for (int a = 0; a < 4; ++a) {
        float s0v = sv0[a], s1v = sv1[a];
#pragma unroll
        for (int l = 0; l < 4; ++l) {
          acc[0][a][0][l] += s0v * kv0[l];
          acc[0][a][1][l] += s0v * kv1[l];
          acc[1][a][0][l] += s1v * kv0[l];
          acc[1][a][1][l] += s1v * kv1[l];
        }
      }
    }

    if (more) {
      *(f4*)&sK[b ^ 1][kr][kcol * 4] = kpre;
      if (tid < Pn) {
        f4 pv[4] = {spre0, spre1, spre2, spre3};
#pragma unroll
        for (int i4 = 0; i4 < ST / 4; ++i4) {
#pragma unroll
          for (int j = 0; j < 4; ++j) {
            float x = pv[i4][j] * w;
            s = fminf(fmaxf(s, x), x + 1.0f);
            sS[b ^ 1][i4 * 4 + j][tid] = s;
          }
        }
      }
    }
    __syncthreads();
    b ^= 1;
  }

  if (ATOMIC) {
#pragma unroll
    for (int k1 = 0; k1 < 2; ++k1)
#pragma unroll
      for (int a = 0; a < 4; ++a) {
        int pp = k1 * 128 + pg * 4 + a;
#pragma unroll
        for (int k2 = 0; k2 < 2; ++k2)
#pragma unroll
          for (int l = 0; l < 4; ++l)
            atomicAdd(&outp[(size_t)pp * Un + k2 * 64 + ug * 4 + l],
                      acc[k1][a][k2][l]);
      }
  } else {
    float* base = outp + (size_t)blockIdx.x * (Pn * Un);
#pragma unroll
    for (int k1 = 0; k1 < 2; ++k1)
#pragma unroll
      for (int a = 0; a < 4; ++a) {
        int pp = k1 * 128 + pg * 4 + a;
#pragma unroll
        for (int k2 = 0; k2 < 2; ++k2) {
          f4 v;
#pragma unroll
          for (int l = 0; l < 4; ++l) v[l] = acc[k1][a][k2][l];
          *(f4*)&base[(size_t)pp * Un + k2 * 64 + ug * 4] = v;
        }
      }
  }
}

// ---------------------------------------------------------------------------
// kD: reduce NP partial planes + bias + tanh, built for MLP.
// 1024 blocks x 256 threads (4 blocks/CU, 16 waves/CU). Block owns 8 f4 of
// output (g4 = blk*8 + fi). Thread (fi=t&7, pg=t>>3): reduce NP/32 planes
// with independent 128B-segment f4 loads. LDS 32->1 combine, f4 tanh store.
// ---------------------------------------------------------------------------
template <int NP>
__global__ __launch_bounds__(256) void kD(const float* __restrict__ part,
                                          const float* __restrict__ bias,
                                          float* __restrict__ out) {
  __shared__ f4 red[32][8];
  const int tid = threadIdx.x;
  const int fi = tid & 7, pg = tid >> 3;   // 32 plane-groups
  constexpr int PPG = NP / 32;             // planes per group
  const f4* p4 = (const f4*)part;
  const size_t g4 = (size_t)blockIdx.x * 8 + fi;

  f4 acc = {0.0f, 0.0f, 0.0f, 0.0f};
#pragma unroll
  for (int k = 0; k < PPG; ++k) {
    f4 v = p4[(size_t)(pg * PPG + k) * (Pn * Un / 4) + g4];
    acc.x += v.x; acc.y += v.y; acc.z += v.z; acc.w += v.w;
  }
  red[pg][fi] = acc;
  __syncthreads();

  if (tid < 8) {
    f4 s = red[0][tid];
#pragma unroll
    for (int q = 1; q < 32; ++q) {
      f4 v = red[q][tid];
      s.x += v.x; s.y += v.y; s.z += v.z; s.w += v.w;
    }
    f4 bv = ((const f4*)bias)[(int)(g4 & 31)];
    f4 o;
    o.x = tanhf(s.x + bv.x);
    o.y = tanhf(s.y + bv.y);
    o.z = tanhf(s.z + bv.z);
    o.w = tanhf(s.w + bv.w);
    ((f4*)out)[g4] = o;
  }
}

// tanh finisher for atomic last-resort path
__global__ __launch_bounds__(256) void kD2(float* __restrict__ out,
                                           const float* __restrict__ bias) {
  const int g = blockIdx.x * 256 + threadIdx.x;
  out[g] = tanhf(out[g] + bias[g & (Un - 1)]);
}

// ---------------------------------------------------------------------------
extern "C" void kernel_launch(void* const* d_in, const int* in_sizes, int n_in,
                              void* d_out, int out_size, void* d_ws,
                              size_t ws_size, hipStream_t stream) {
  const float* in   = (const float*)d_in[0];  // [P, T]
  const float* pw   = (const float*)d_in[1];  // [P]
  const float* Kg   = (const float*)d_in[2];  // [T, U]
  const float* bias = (const float*)d_in[3];  // [U]
  const float* st   = (const float*)d_in[4];  // [P]
  float* out = (float*)d_out;                 // [P, U]
  float* wsf = (float*)d_ws;

  f2* AB      = (f2*)wsf;                     // Pn*NC f2     (1 MB)
  float* sinb = wsf + 2 * NC * Pn;            // NC*Pn floats (0.5 MB)
  float* part = wsf + 3 * NC * Pn;            // partial planes

  const size_t base_f = (size_t)3 * NC * Pn;
  const size_t need1 = (base_f + (size_t)NC * Pn * Un) * 4;        // ~68.7 MB
  const size_t need2 = (base_f + (size_t)(NC / 2) * Pn * Un) * 4;  // ~35.1 MB

  kA<<<(Pn * NC) / 16, 1024, 0, stream>>>(in, pw, AB);
  kB<<<Pn, NC, 0, stream>>>(AB, st, sinb);

  if (ws_size >= need1) {
    kC<1, false><<<NC, 512, 0, stream>>>(in, pw, Kg, sinb, part);
    kD<NC><<<(Pn * Un / 4) / 8, 256, 0, stream>>>(part, bias, out);
  } else if (ws_size >= need2) {
    kC<2, false><<<NC / 2, 512, 0, stream>>>(in, pw, Kg, sinb, part);
    kD<NC / 2><<<(Pn * Un / 4) / 8, 256, 0, stream>>>(part, bias, out);
  } else {
    hipMemsetAsync(out, 0, (size_t)Pn * Un * sizeof(float), stream);
    kC<2, true><<<NC / 2, 512, 0, stream>>>(in, pw, Kg, sinb, out);
    kD2<<<(Pn * Un) / 256, 256, 0, stream>>>(out, bias);
  }
}